// Round 4
// baseline (224.356 us; speedup 1.0000x reference)
//
#include <hip/hip_runtime.h>
#include <hip/hip_bf16.h>

// ContrastiveLoss: loss = mean_i [ logsumexp_j(logits[i,:]) - pos_sim[i,i] ]
// logits = [20*xn@tn^T | 20*xn@hn^T + I], rows normalized.
// Round 4: MX-fp8 via mfma_scale_f32_16x16x128_f8f6f4 (unit scales).
//  - 16x16x128 keeps f32x4 accumulators -> ~180 regs (round-2's 32x32x64
//    needed f32x16 and hit the 256-VGPR ceiling + 72MB spill traffic)
//  - halves LDS bytes/FLOP vs bf16 AND doubles MFMA rate (ladder m148: 1628TF)
//  - m97-style single-buffered 2-barrier K-loop, BK=128 bytes, 8 K-steps
//  - XOR swizzle phys16B = log ^ (row&7): each 8-lane b128 phase hits all
//    32 banks (round-3's swizzle was ineffective: conflict counter unchanged)
//  - normalize emits fp8 directly (one row/wave, shfl-only reduce)

#define AS1 __attribute__((address_space(1)))
#define AS3 __attribute__((address_space(3)))

constexpr int N = 4096;
constexpr int D = 1024;            // elements per row == bytes per fp8 row
constexpr float TEMP_INV = 20.0f;  // 1/0.05
constexpr float CBIAS = 21.0f;     // >= max possible logit (20*1 + 1)

typedef float f32x4 __attribute__((ext_vector_type(4)));
typedef int i32x4 __attribute__((ext_vector_type(4)));
typedef int i32x8 __attribute__((ext_vector_type(8)));

// 3072 blocks x 256. One row per wave (4 rows/block); lane holds 16 floats.
// Blocks 0..15 also zero rowsum so gemm's atomics start clean.
__global__ __launch_bounds__(256) void normalize_kernel(
    const float* __restrict__ in0, const float* __restrict__ in1,
    const float* __restrict__ in2, unsigned int* __restrict__ Abuf,
    unsigned int* __restrict__ Bbuf, float* __restrict__ rowsum) {
    const int t = threadIdx.x, lane = t & 63, wave = t >> 6;
    if (blockIdx.x < 16) rowsum[blockIdx.x * 256 + t] = 0.f;
    const int row = blockIdx.x * 4 + wave;  // 0..12287
    const int mat = row >> 12, r = row & (N - 1);
    const float* src = (mat == 0) ? in0 : (mat == 1) ? in1 : in2;
    unsigned int* dst = (mat == 0) ? (Abuf + (size_t)r * (D / 4))
                      : (mat == 1) ? (Bbuf + (size_t)r * (D / 4))
                                   : (Bbuf + (size_t)(r + N) * (D / 4));
    const float4* s4 = (const float4*)(src + (size_t)r * D);
    float4 v[4];
    float p = 0.f;
#pragma unroll
    for (int j = 0; j < 4; ++j) {
        v[j] = s4[lane + 64 * j];
        p += v[j].x * v[j].x + v[j].y * v[j].y + v[j].z * v[j].z + v[j].w * v[j].w;
    }
#pragma unroll
    for (int m = 1; m < 64; m <<= 1) p += __shfl_xor(p, m);
    const float inv = 1.0f / fmaxf(sqrtf(p), 1e-8f);
#pragma unroll
    for (int j = 0; j < 4; ++j) {
        unsigned int pk = __builtin_amdgcn_cvt_pk_fp8_f32(v[j].x * inv, v[j].y * inv, 0, false);
        pk = __builtin_amdgcn_cvt_pk_fp8_f32(v[j].z * inv, v[j].w * inv, pk, true);
        dst[lane + 64 * j] = pk;  // coalesced 256B/wave dword stores
    }
}

// 128x128 tile, BK=128 fp8-bytes, 4 waves 2x2, wave 64x64 via 4x4 of
// 16x16x128 MX-fp8 (unit scales). A:[N,D] fp8, B:[2N,D] fp8, row-major.
// A-frag: row = lane&15, k = (lane>>4)*32 + j (one contiguous 32B K-block
// per lane — same principle as the round-2-verified 32x32x64 layout).
// C/D: col = lane&15, row = (lane>>4)*4 + reg (m89-verified, shape-determined).
__global__ __launch_bounds__(256) void gemm_lse_kernel(
    const unsigned char* __restrict__ A, const unsigned char* __restrict__ B,
    float* __restrict__ rowsum, float* __restrict__ posdiag) {
    __shared__ __align__(16) char As[128 * 128];  // 16 KiB
    __shared__ __align__(16) char Bs[128 * 128];  // 16 KiB

    const int tid = threadIdx.x;
    const int lane = tid & 63;
    const int wave = tid >> 6;
    const int wr = wave >> 1, wc = wave & 1;
    const int quad = lane >> 4, colid = lane & 15;
    const int rowBase = blockIdx.y * 128;
    const int colBase = blockIdx.x * 128;

    f32x4 acc[4][4];
#pragma unroll
    for (int i = 0; i < 4; ++i)
#pragma unroll
        for (int j = 0; j < 4; ++j) acc[i][j] = {0.f, 0.f, 0.f, 0.f};

    // Staging: 1024 16B-chunks per 128x128B tile; thread t fills chunks
    // c = t + 256j (LDS byte c*16). Source: row = c>>3 = (t>>3)+32j,
    // logical col = (c&7) ^ (row&7)  (self-inverse XOR; row&7 is j-invariant).
    const int srow = tid >> 3;                       // 0..31
    const int scol = (tid & 7) ^ ((tid >> 3) & 7);   // 16B units
    const unsigned char* gA[4];
    const unsigned char* gB[4];
#pragma unroll
    for (int j = 0; j < 4; ++j) {
        gA[j] = A + (size_t)(rowBase + srow + 32 * j) * D + scol * 16;
        gB[j] = B + (size_t)(colBase + srow + 32 * j) * D + scol * 16;
    }

    // Loop-invariant frag byte offsets: frag = 32B = 2 x b128 chunks.
    // Row R, logical chunk q=quad*2+c sits at phys q ^ (R&7).
    int aoff[4][2], boff[4][2];
#pragma unroll
    for (int rt = 0; rt < 4; ++rt) {
        const int R = wr * 64 + rt * 16 + colid;
#pragma unroll
        for (int c = 0; c < 2; ++c)
            aoff[rt][c] = R * 128 + ((quad * 2 + c) ^ (R & 7)) * 16;
    }
#pragma unroll
    for (int ct = 0; ct < 4; ++ct) {
        const int C = wc * 64 + ct * 16 + colid;
#pragma unroll
        for (int c = 0; c < 2; ++c)
            boff[ct][c] = C * 128 + ((quad * 2 + c) ^ (C & 7)) * 16;
    }

    for (int kb = 0; kb < D / 128; ++kb) {
        const int k0 = kb * 128;
        __syncthreads();  // prior reads done before overwrite
#pragma unroll
        for (int j = 0; j < 4; ++j) {
            __builtin_amdgcn_global_load_lds((const AS1 void*)(gA[j] + k0),
                (AS3 void*)(As + (j * 256 + wave * 64) * 16), 16, 0, 0);
            __builtin_amdgcn_global_load_lds((const AS1 void*)(gB[j] + k0),
                (AS3 void*)(Bs + (j * 256 + wave * 64) * 16), 16, 0, 0);
        }
        __syncthreads();  // staged data visible

        i32x8 av[4], bv[4];
#pragma unroll
        for (int rt = 0; rt < 4; ++rt) {
            i32x4 lo = *(const i32x4*)(As + aoff[rt][0]);
            i32x4 hi = *(const i32x4*)(As + aoff[rt][1]);
            av[rt] = __builtin_shufflevector(lo, hi, 0, 1, 2, 3, 4, 5, 6, 7);
        }
#pragma unroll
        for (int ct = 0; ct < 4; ++ct) {
            i32x4 lo = *(const i32x4*)(Bs + boff[ct][0]);
            i32x4 hi = *(const i32x4*)(Bs + boff[ct][1]);
            bv[ct] = __builtin_shufflevector(lo, hi, 0, 1, 2, 3, 4, 5, 6, 7);
        }
#pragma unroll
        for (int rt = 0; rt < 4; ++rt)
#pragma unroll
            for (int ct = 0; ct < 4; ++ct)
                acc[rt][ct] = __builtin_amdgcn_mfma_scale_f32_16x16x128_f8f6f4(
                    av[rt], bv[ct], acc[rt][ct],
                    0 /*fmtA=fp8*/, 0 /*fmtB=fp8*/,
                    0, 0x7F7F7F7F, 0, 0x7F7F7F7F /*unit E8M0 scales*/);
    }

    // Epilogue: C map col = lane&15, row = quad*4 + reg.
#pragma unroll
    for (int rt = 0; rt < 4; ++rt) {
        float rsum[4] = {0.f, 0.f, 0.f, 0.f};
#pragma unroll
        for (int ct = 0; ct < 4; ++ct) {
#pragma unroll
            for (int reg = 0; reg < 4; ++reg) {
                const int grow = rowBase + wr * 64 + rt * 16 + quad * 4 + reg;
                const int gcol = colBase + wc * 64 + ct * 16 + colid;
                float logit = acc[rt][ct][reg] * TEMP_INV;
                if (gcol == grow + N) logit += 1.0f;      // hard-negative weight
                if (gcol == grow) posdiag[grow] = logit;  // unique writer
                rsum[reg] += __expf(logit - CBIAS);
            }
        }
#pragma unroll
        for (int reg = 0; reg < 4; ++reg) {
            float v = rsum[reg];
            v += __shfl_xor(v, 1);
            v += __shfl_xor(v, 2);
            v += __shfl_xor(v, 4);
            v += __shfl_xor(v, 8);
            if (colid == 0) {
                const int grow = rowBase + wr * 64 + rt * 16 + quad * 4 + reg;
                atomicAdd(&rowsum[grow], v);
            }
        }
    }
}

__global__ __launch_bounds__(256) void finalize_kernel(
    const float* __restrict__ rowsum, const float* __restrict__ posdiag,
    float* __restrict__ out) {
    const int t = threadIdx.x;
    float s = 0.f;
    for (int i = t; i < N; i += 256)
        s += CBIAS + logf(rowsum[i]) - posdiag[i];
    for (int m = 32; m; m >>= 1) s += __shfl_down(s, m);
    __shared__ float red[4];
    const int lane = t & 63, wave = t >> 6;
    if (lane == 0) red[wave] = s;
    __syncthreads();
    if (t == 0) out[0] = (red[0] + red[1] + red[2] + red[3]) / (float)N;
}

extern "C" void kernel_launch(void* const* d_in, const int* in_sizes, int n_in,
                              void* d_out, int out_size, void* d_ws, size_t ws_size,
                              hipStream_t stream) {
    const float* in0 = (const float*)d_in[0];  // input   [N, D] fp32
    const float* in1 = (const float*)d_in[1];  // target  [N, D] fp32
    const float* in2 = (const float*)d_in[2];  // hardneg [N, D] fp32

    // Workspace: Abuf N*D fp8 (4 MiB) | Bbuf 2N*D fp8 (8 MiB) | rowsum | posdiag
    unsigned char* Abuf = (unsigned char*)d_ws;
    unsigned char* Bbuf = Abuf + (size_t)N * D;
    float* rowsum = (float*)(Bbuf + (size_t)2 * N * D);
    float* posdiag = rowsum + N;

    normalize_kernel<<<3 * N / 4, 256, 0, stream>>>(
        in0, in1, in2, (unsigned int*)Abuf, (unsigned int*)Bbuf, rowsum);
    gemm_lse_kernel<<<dim3(2 * N / 128, N / 128), 256, 0, stream>>>(
        Abuf, Bbuf, rowsum, posdiag);
    finalize_kernel<<<1, 256, 0, stream>>>(rowsum, posdiag, (float*)d_out);
}